// Round 15
// baseline (230.718 us; speedup 1.0000x reference)
//
#include <hip/hip_runtime.h>
#include <hip/hip_bf16.h>

#define N_NODES 50000
#define N_EDGES 640000
#define DUMMY   N_NODES
#define CAP     56        // fixed slots/node; P(deg>=56) ~ 4e-35 for Poisson(12.8)
#define NBUCK   196       // node buckets of 256: (50000+255)/256
#define EBLK    2500      // edge blocks of 256
#define NCHUNK  12500     // per-column stat chunks (one per agg block)
// FEAT = EMB = 128, HID = 512, B = 32

typedef __attribute__((ext_vector_type(8))) short short8;   // 8 x bf16 (4 VGPRs)
typedef __attribute__((ext_vector_type(4))) float floatx4;  // MFMA C/D

__device__ __forceinline__ float bf2f(unsigned short u) {
    return __uint_as_float(((unsigned int)u) << 16);
}
__device__ __forceinline__ unsigned short f2bf(float x) {
    unsigned int u = __float_as_uint(x);
    u = (u + 0x7fffu + ((u >> 16) & 1u)) >> 16;   // RNE
    return (unsigned short)u;
}
__device__ __forceinline__ unsigned char f2f8(float x) {
    int pk = __builtin_amdgcn_cvt_pk_fp8_f32(x, x, 0, false);  // OCP e4m3 on gfx950
    return (unsigned char)(pk & 0xff);
}
__device__ __forceinline__ unsigned int pk4_fp8(float x0, float x1, float x2, float x3) {
    int v = __builtin_amdgcn_cvt_pk_fp8_f32(x0, x1, 0, false);
    v = __builtin_amdgcn_cvt_pk_fp8_f32(x2, x3, v, true);
    return (unsigned int)v;
}
__device__ __forceinline__ unsigned int pk2_bf16(float lo, float hi) {
    return (unsigned int)f2bf(lo) | ((unsigned int)f2bf(hi) << 16);
}

// ---- prep: coarse LDS histogram (dst>>8, NO device atomics) | weights | meb | dummy ----
__global__ void __launch_bounds__(256) prep_k(const float* __restrict__ W0,
                                              const float* __restrict__ W1,
                                              const float* __restrict__ W2,
                                              const float* __restrict__ W3,
                                              unsigned short* __restrict__ T0,
                                              unsigned short* __restrict__ T1,
                                              unsigned short* __restrict__ T2,
                                              unsigned short* __restrict__ T3,
                                              const float* __restrict__ lh,
                                              const float* __restrict__ Wp,
                                              const float* __restrict__ bp,
                                              unsigned short* __restrict__ meb,
                                              unsigned char* __restrict__ tbf,
                                              const int* __restrict__ dst,
                                              int* __restrict__ blockcnt) {
    __shared__ int h[NBUCK];
    int b = blockIdx.x, tid = threadIdx.x;
    bool is_hist;
    int idx;
    if (b < 546) { is_hist = ((b & 1) == 0); idx = b >> 1; }
    else         { is_hist = true;            idx = 273 + (b - 546); }
    if (is_hist) {                        // coarse hist: 2500 blocks, LDS atomics only
        if (tid < NBUCK) h[tid] = 0;
        __syncthreads();
        int e = idx * 256 + tid;          // exactly 640000
        int bk = (dst[e] >> 8) & 255;
        if (bk < NBUCK) atomicAdd(&h[bk], 1);
        __syncthreads();
        if (tid < NBUCK) blockcnt[tid * EBLK + idx] = h[tid];
        return;
    }
    int s = idx;
    if (s < 256) {                        // pack weights transposed: 65536
        int i2 = s * 256 + tid;
        int w = i2 >> 14;
        int r = i2 & 16383;
        int n = r >> 7, k = r & 127;
        const float* W = (w == 0) ? W0 : (w == 1) ? W1 : (w == 2) ? W2 : W3;
        unsigned short* T = (w == 0) ? T0 : (w == 1) ? T1 : (w == 2) ? T2 : T3;
        T[r] = f2bf(W[k * 128 + n]);
    } else if (s < 272) {                 // message embed: 4096 outputs
        int o = (s - 256) * 256 + tid;
        int i = o >> 7, c = o & 127;
        float acc = bp[c];
        const float4* lr = (const float4*)(lh + i * 512);
        #pragma unroll 4
        for (int k4 = 0; k4 < 128; k4++) {
            float4 v = lr[k4];
            acc += v.x * Wp[(4 * k4 + 0) * 128 + c] + v.y * Wp[(4 * k4 + 1) * 128 + c]
                 + v.z * Wp[(4 * k4 + 2) * 128 + c] + v.w * Wp[(4 * k4 + 3) * 128 + c];
        }
        meb[o] = f2bf(acc);
    } else {                              // zero dummy fp8 row (128 B)
        if (tid < 32) ((unsigned int*)(tbf + (size_t)DUMMY * 128))[tid] = 0;
    }
}

// ---- scan: per bucket, exclusive scan of blockcnt over 2500 edge-blocks ----
__global__ void __launch_bounds__(256) scan_k(int* __restrict__ blockcnt,
                                              int* __restrict__ totals) {
    __shared__ int sm[256];
    int b = blockIdx.x, t = threadIdx.x;
    int running = 0;
    for (int c = 0; c < 10; c++) {
        int i = c * 256 + t;
        int v = (i < EBLK) ? blockcnt[b * EBLK + i] : 0;
        sm[t] = v;
        __syncthreads();
        for (int off = 1; off < 256; off <<= 1) {
            int u = (t >= off) ? sm[t - off] : 0;
            __syncthreads();
            sm[t] += u;
            __syncthreads();
        }
        if (i < EBLK) blockcnt[b * EBLK + i] = running + sm[t] - v;   // exclusive
        int ctot = sm[255];
        __syncthreads();
        running += ctot;
    }
    if (t == 0) totals[b] = running;
}

// ---- scatter: bucket-group edges into pairs[] (LDS-ranked, NO device atomics) ----
__global__ void __launch_bounds__(256) scatter_k(const int* __restrict__ src,
                                                 const int* __restrict__ dst,
                                                 const int* __restrict__ blockcnt,
                                                 const int* __restrict__ totals,
                                                 unsigned int* __restrict__ pairs) {
    __shared__ int offl[NBUCK];
    __shared__ int sm[256];
    int blk = blockIdx.x, t = threadIdx.x;
    int tv = (t < NBUCK) ? totals[t] : 0;
    sm[t] = tv;
    __syncthreads();
    for (int off = 1; off < 256; off <<= 1) {
        int u = (t >= off) ? sm[t - off] : 0;
        __syncthreads();
        sm[t] += u;
        __syncthreads();
    }
    if (t < NBUCK) offl[t] = (sm[t] - tv) + blockcnt[t * EBLK + blk];
    __syncthreads();
    int e = blk * 256 + t;
    int d = dst[e], s = src[e];
    int bk = (d >> 8) & 255;
    if (bk < NBUCK) {
        int pos = atomicAdd(&offl[bk], 1);          // LDS atomic
        if ((unsigned)pos < (unsigned)N_EDGES)      // defensive bound (fault guard)
            pairs[pos] = ((unsigned int)s << 16) | (unsigned int)(d & 0xffff);
    }
}

// ---- dual GEMM, 32-row tiles, LDS-staged A and B (coalesced global reads) ----
#define EPI_LD 132   // epilogue row stride in dwords
template <bool AF32>
__device__ __forceinline__ void gemm_dual_lds32(int bid, int tid,
                                                const void* __restrict__ Ain,
                                                const unsigned short* __restrict__ BtRel,
                                                const unsigned short* __restrict__ BtRoot,
                                                unsigned char* __restrict__ Trel,
                                                unsigned short* __restrict__ Rootb,
                                                int M, char* __restrict__ pool) {
    int wid = tid >> 6, lane = tid & 63;
    int m = lane & 15, g = lane >> 4;
    int r0 = bid * 32;
    if constexpr (AF32) {
        const float* A = (const float*)Ain;
        #pragma unroll
        for (int j = 0; j < 2; j++) {
            int k = j * 256 + tid;
            int row = k >> 4;
            int grow = r0 + row; grow = (grow < M) ? grow : (M - 1);
            const float* p = A + (size_t)grow * 128 + (k & 15) * 8;
            float4 v0 = *(const float4*)p;
            float4 v1 = *(const float4*)(p + 4);
            short8 t8;
            t8[0] = (short)f2bf(v0.x); t8[1] = (short)f2bf(v0.y);
            t8[2] = (short)f2bf(v0.z); t8[3] = (short)f2bf(v0.w);
            t8[4] = (short)f2bf(v1.x); t8[5] = (short)f2bf(v1.y);
            t8[6] = (short)f2bf(v1.z); t8[7] = (short)f2bf(v1.w);
            *(short8*)(pool + ((k * 16) ^ ((row & 7) << 4))) = t8;
        }
    } else {
        const unsigned short* A = (const unsigned short*)Ain;
        #pragma unroll
        for (int j = 0; j < 2; j++) {
            int k = j * 256 + tid;
            int row = k >> 4;
            int grow = r0 + row; grow = (grow < M) ? grow : (M - 1);
            short8 v = *(const short8*)(A + (size_t)grow * 128 + (k & 15) * 8);
            *(short8*)(pool + ((k * 16) ^ ((row & 7) << 4))) = v;
        }
    }
    #pragma unroll
    for (int j = 0; j < 8; j++) {
        int k = j * 256 + tid;
        int row = k >> 4;
        short8 v = *(const short8*)(BtRel + (size_t)k * 8);
        *(short8*)(pool + 8192 + ((k * 16) ^ ((row & 7) << 4))) = v;
    }
    __syncthreads();
    int lrow = (wid >> 1) * 16 + m;
    int asw = (lrow & 7) << 4, abase = lrow * 256;
    short8 a[4];
    #pragma unroll
    for (int kt = 0; kt < 4; kt++)
        a[kt] = *(const short8*)(pool + ((abase + kt * 64 + g * 16) ^ asw));
    int browbase = (wid & 1) * 64;
    floatx4 accR[4], accO[4];
    #pragma unroll
    for (int ct = 0; ct < 4; ct++) {
        accR[ct] = (floatx4)(0.f);
        int brow = browbase + ct * 16 + m;
        int bbase = brow * 256, bsw = (brow & 7) << 4;
        #pragma unroll
        for (int kt = 0; kt < 4; kt++) {
            short8 bv = *(const short8*)(pool + 8192 + ((bbase + kt * 64 + g * 16) ^ bsw));
            accR[ct] = __builtin_amdgcn_mfma_f32_16x16x32_bf16(a[kt], bv, accR[ct], 0, 0, 0);
        }
    }
    __syncthreads();
    #pragma unroll
    for (int j = 0; j < 8; j++) {
        int k = j * 256 + tid;
        int row = k >> 4;
        short8 v = *(const short8*)(BtRoot + (size_t)k * 8);
        *(short8*)(pool + 8192 + ((k * 16) ^ ((row & 7) << 4))) = v;
    }
    __syncthreads();
    #pragma unroll
    for (int ct = 0; ct < 4; ct++) {
        accO[ct] = (floatx4)(0.f);
        int brow = browbase + ct * 16 + m;
        int bbase = brow * 256, bsw = (brow & 7) << 4;
        #pragma unroll
        for (int kt = 0; kt < 4; kt++) {
            short8 bv = *(const short8*)(pool + 8192 + ((bbase + kt * 64 + g * 16) ^ bsw));
            accO[ct] = __builtin_amdgcn_mfma_f32_16x16x32_bf16(a[kt], bv, accO[ct], 0, 0, 0);
        }
    }
    __syncthreads();
    float* epi = (float*)(pool + 8192);
    int rh = (wid >> 1) * 16, ch = (wid & 1) * 64;
    #pragma unroll
    for (int ct = 0; ct < 4; ct++)
        #pragma unroll
        for (int rg = 0; rg < 4; rg++)
            epi[(rh + g * 4 + rg) * EPI_LD + ch + ct * 16 + m] = accR[ct][rg];
    __syncthreads();
    {
        int lr = tid >> 3, c0 = (tid & 7) * 16;
        int ro = r0 + lr;
        const float* row = epi + lr * EPI_LD + c0;
        if (ro < M) {
            uint4 w;
            w.x = pk4_fp8(row[0],  row[1],  row[2],  row[3]);
            w.y = pk4_fp8(row[4],  row[5],  row[6],  row[7]);
            w.z = pk4_fp8(row[8],  row[9],  row[10], row[11]);
            w.w = pk4_fp8(row[12], row[13], row[14], row[15]);
            *(uint4*)(Trel + (size_t)ro * 128 + c0) = w;
        }
    }
    __syncthreads();
    #pragma unroll
    for (int ct = 0; ct < 4; ct++)
        #pragma unroll
        for (int rg = 0; rg < 4; rg++)
            epi[(rh + g * 4 + rg) * EPI_LD + ch + ct * 16 + m] = accO[ct][rg];
    __syncthreads();
    {
        int lr = tid >> 3, c0 = (tid & 7) * 16;
        int ro = r0 + lr;
        const float* row = epi + lr * EPI_LD + c0;
        if (ro < M) {
            uint4 w0, w1;
            w0.x = pk2_bf16(row[0],  row[1]);
            w0.y = pk2_bf16(row[2],  row[3]);
            w0.z = pk2_bf16(row[4],  row[5]);
            w0.w = pk2_bf16(row[6],  row[7]);
            w1.x = pk2_bf16(row[8],  row[9]);
            w1.y = pk2_bf16(row[10], row[11]);
            w1.z = pk2_bf16(row[12], row[13]);
            w1.w = pk2_bf16(row[14], row[15]);
            *(uint4*)(Rootb + (size_t)ro * 128 + c0) = w0;
            *(uint4*)(Rootb + (size_t)ro * 128 + c0 + 8) = w1;
        }
    }
}

// ---- placement (blocks 0..195: one bucket each, LDS ranks) | layer-1 dual GEMM ----
__global__ void __launch_bounds__(256) placegemm_k(const int* __restrict__ totals,
                                                   const unsigned int* __restrict__ pairs,
                                                   unsigned short* __restrict__ ssrc,
                                                   int* __restrict__ cnt,
                                                   const float* __restrict__ A,
                                                   const unsigned short* __restrict__ BtRel,
                                                   const unsigned short* __restrict__ BtRoot,
                                                   unsigned char* __restrict__ Trel,
                                                   unsigned short* __restrict__ Rootb) {
    __shared__ __align__(16) char pool[40960];
    int t = threadIdx.x;
    if (blockIdx.x >= NBUCK) {
        gemm_dual_lds32<true>(blockIdx.x - NBUCK, t, A, BtRel, BtRoot,
                              Trel, Rootb, N_NODES, pool);
        return;
    }
    int b = blockIdx.x;
    int* lcnt = (int*)pool;               // [256]
    int* sm   = (int*)(pool + 1024);      // [256]
    int* sb   = (int*)(pool + 2048);      // [1]
    int tv = (t < NBUCK) ? totals[t] : 0;
    sm[t] = tv;
    __syncthreads();
    for (int off = 1; off < 256; off <<= 1) {
        int u = (t >= off) ? sm[t - off] : 0;
        __syncthreads();
        sm[t] += u;
        __syncthreads();
    }
    if (t == b) *sb = sm[t] - tv;         // exclusive base of bucket b
    lcnt[t] = 0;
    __syncthreads();
    int base = *sb;
    int n = totals[b];
    if (n > N_EDGES) n = N_EDGES;         // defensive
    for (int i = t; i < n; i += 256) {
        int gi = base + i;
        if ((unsigned)gi >= (unsigned)N_EDGES) break;   // defensive
        unsigned int p = pairs[gi];
        int dl = (int)(p & 0xffu);
        int d = b * 256 + dl;
        int s = (int)(p >> 16);
        int r = atomicAdd(&lcnt[dl], 1);                // LDS atomic
        if (d < N_NODES && r < CAP)
            ssrc[(size_t)d * CAP + r] = (unsigned short)s;
    }
    __syncthreads();
    int node = b * 256 + t;
    if (node < N_NODES) cnt[node] = lcnt[t];
}

// ---- layer-2 dual GEMM (bf16 A) ----
__global__ void __launch_bounds__(256) gemm_dual_k(const unsigned short* __restrict__ A,
                                                   const unsigned short* __restrict__ BtRel,
                                                   const unsigned short* __restrict__ BtRoot,
                                                   unsigned char* __restrict__ Trel,
                                                   unsigned short* __restrict__ Rootb, int M) {
    __shared__ __align__(16) char pool[40960];
    gemm_dual_lds32<false>(blockIdx.x, threadIdx.x, A, BtRel, BtRoot, Trel, Rootb, M, pool);
}

// ---- shared gather core: node's mean-agg h (4 feats/lane on lanes<32) ----
__device__ __forceinline__ void agg_core(int node, int lane,
                                         const int* __restrict__ cnt,
                                         const unsigned short* __restrict__ ssrc,
                                         const unsigned char* __restrict__ t,
                                         float& A0, float& A1, float& A2, float& A3,
                                         int& DEG) {
    int fl = lane & 31;
    int sh = (lane & 32) >> 1;
    int beg = node * CAP;
    int deg = cnt[node];
    deg = (deg < CAP) ? deg : CAP;
    int pad = (deg + 7) & ~7;
    const unsigned char* tf = t + fl * 4;
    float a0=0.f,a1=0.f,a2=0.f,a3=0.f;
    float b0=0.f,b1=0.f,b2=0.f,b3=0.f;
    int s0base = sh >> 4;
    for (int k = 0; k < pad; k += 16) {
        const unsigned short* sp = ssrc + beg + k;
        uint4 w0 = *(const uint4*)sp;
        uint4 w1 = (k + 8 < pad) ? *(const uint4*)(sp + 8) : make_uint4(0u, 0u, 0u, 0u);
        int s0 = k + s0base;
        int i0 = (s0 +  0 < deg) ? (int)((w0.x >> sh) & 0xffffu) : DUMMY;
        int i1 = (s0 +  2 < deg) ? (int)((w0.y >> sh) & 0xffffu) : DUMMY;
        int i2 = (s0 +  4 < deg) ? (int)((w0.z >> sh) & 0xffffu) : DUMMY;
        int i3 = (s0 +  6 < deg) ? (int)((w0.w >> sh) & 0xffffu) : DUMMY;
        int i4 = (s0 +  8 < deg) ? (int)((w1.x >> sh) & 0xffffu) : DUMMY;
        int i5 = (s0 + 10 < deg) ? (int)((w1.y >> sh) & 0xffffu) : DUMMY;
        int i6 = (s0 + 12 < deg) ? (int)((w1.z >> sh) & 0xffffu) : DUMMY;
        int i7 = (s0 + 14 < deg) ? (int)((w1.w >> sh) & 0xffffu) : DUMMY;
        unsigned int u0 = *(const unsigned int*)(tf + (size_t)i0 * 128);
        unsigned int u1 = *(const unsigned int*)(tf + (size_t)i1 * 128);
        unsigned int u2 = *(const unsigned int*)(tf + (size_t)i2 * 128);
        unsigned int u3 = *(const unsigned int*)(tf + (size_t)i3 * 128);
        unsigned int u4 = *(const unsigned int*)(tf + (size_t)i4 * 128);
        unsigned int u5 = *(const unsigned int*)(tf + (size_t)i5 * 128);
        unsigned int u6 = *(const unsigned int*)(tf + (size_t)i6 * 128);
        unsigned int u7 = *(const unsigned int*)(tf + (size_t)i7 * 128);
        a0 += __builtin_amdgcn_cvt_f32_fp8(u0, 0) + __builtin_amdgcn_cvt_f32_fp8(u1, 0);
        a1 += __builtin_amdgcn_cvt_f32_fp8(u0, 1) + __builtin_amdgcn_cvt_f32_fp8(u1, 1);
        a2 += __builtin_amdgcn_cvt_f32_fp8(u0, 2) + __builtin_amdgcn_cvt_f32_fp8(u1, 2);
        a3 += __builtin_amdgcn_cvt_f32_fp8(u0, 3) + __builtin_amdgcn_cvt_f32_fp8(u1, 3);
        b0 += __builtin_amdgcn_cvt_f32_fp8(u2, 0) + __builtin_amdgcn_cvt_f32_fp8(u3, 0);
        b1 += __builtin_amdgcn_cvt_f32_fp8(u2, 1) + __builtin_amdgcn_cvt_f32_fp8(u3, 1);
        b2 += __builtin_amdgcn_cvt_f32_fp8(u2, 2) + __builtin_amdgcn_cvt_f32_fp8(u3, 2);
        b3 += __builtin_amdgcn_cvt_f32_fp8(u2, 3) + __builtin_amdgcn_cvt_f32_fp8(u3, 3);
        a0 += __builtin_amdgcn_cvt_f32_fp8(u4, 0) + __builtin_amdgcn_cvt_f32_fp8(u5, 0);
        a1 += __builtin_amdgcn_cvt_f32_fp8(u4, 1) + __builtin_amdgcn_cvt_f32_fp8(u5, 1);
        a2 += __builtin_amdgcn_cvt_f32_fp8(u4, 2) + __builtin_amdgcn_cvt_f32_fp8(u5, 2);
        a3 += __builtin_amdgcn_cvt_f32_fp8(u4, 3) + __builtin_amdgcn_cvt_f32_fp8(u5, 3);
        b0 += __builtin_amdgcn_cvt_f32_fp8(u6, 0) + __builtin_amdgcn_cvt_f32_fp8(u7, 0);
        b1 += __builtin_amdgcn_cvt_f32_fp8(u6, 1) + __builtin_amdgcn_cvt_f32_fp8(u7, 1);
        b2 += __builtin_amdgcn_cvt_f32_fp8(u6, 2) + __builtin_amdgcn_cvt_f32_fp8(u7, 2);
        b3 += __builtin_amdgcn_cvt_f32_fp8(u6, 3) + __builtin_amdgcn_cvt_f32_fp8(u7, 3);
    }
    a0 += b0; a1 += b1; a2 += b2; a3 += b3;
    a0 += __shfl_xor(a0, 32);
    a1 += __shfl_xor(a1, 32);
    a2 += __shfl_xor(a2, 32);
    a3 += __shfl_xor(a3, 32);
    A0 = a0; A1 = a1; A2 = a2; A3 = a3; DEG = deg;
}

// ---- layer-1 aggregate: gather -> hb (bf16) ----
__global__ void __launch_bounds__(256) agg_k(const int* __restrict__ cnt,
                                             const unsigned short* __restrict__ ssrc,
                                             const unsigned char* __restrict__ t,
                                             const unsigned short* __restrict__ rootb,
                                             const float* __restrict__ bias,
                                             unsigned short* __restrict__ hout) {
    int node = blockIdx.x * 4 + (threadIdx.x >> 6);
    if (node >= N_NODES) return;
    int lane = threadIdx.x & 63;
    float a0, a1, a2, a3; int deg;
    agg_core(node, lane, cnt, ssrc, t, a0, a1, a2, a3, deg);
    if ((lane & 32) == 0) {
        float inv = 1.f / fmaxf((float)deg, 1.f);
        int f = (lane & 31) * 4;
        ushort4 r = *(const ushort4*)(rootb + (size_t)node * 128 + f);
        float4 bb = *(const float4*)(bias + f);
        ushort4 o;
        o.x = f2bf(fmaxf(a0 * inv + bf2f(r.x) + bb.x, 0.f));
        o.y = f2bf(fmaxf(a1 * inv + bf2f(r.y) + bb.y, 0.f));
        o.z = f2bf(fmaxf(a2 * inv + bf2f(r.z) + bb.z, 0.f));
        o.w = f2bf(fmaxf(a3 * inv + bf2f(r.w) + bb.w, 0.f));
        *(ushort4*)(hout + (size_t)node * 128 + f) = o;
    }
}

// ---- FUSED layer-2 aggregate + scores (h never leaves the block) ----
// 4 nodes/block (gather parallelism preserved). Per block: gather -> hL (LDS),
// 128 VALU dots vs LDS-staged meb -> sL, coalesced S write, per-block column
// stats -> pm/ps[32][12500]. Eliminates hb round-trip + scores dispatch.
#define MEB_LD 132   // meb LDS row stride in shorts (264B: 2-way bank alias only)
__global__ void __launch_bounds__(256) aggscores_k(const int* __restrict__ cnt,
                                                   const unsigned short* __restrict__ ssrc,
                                                   const unsigned char* __restrict__ t,
                                                   const unsigned short* __restrict__ rootb,
                                                   const float* __restrict__ bias,
                                                   const unsigned short* __restrict__ meb,
                                                   float* __restrict__ S,
                                                   float* __restrict__ pm,
                                                   float* __restrict__ ps) {
    __shared__ unsigned short mebL[32 * MEB_LD];
    __shared__ float hL[4][128];
    __shared__ float sL[4][32];
    int tid = threadIdx.x;
    // stage meb: 4096 shorts, 16/thread, ushort4 (8B-aligned rows)
    {
        int row = tid >> 3, c0 = (tid & 7) * 16;
        const ushort4* gp = (const ushort4*)(meb + row * 128 + c0);
        ushort4* lp = (ushort4*)(&mebL[row * MEB_LD + c0]);
        lp[0] = gp[0]; lp[1] = gp[1]; lp[2] = gp[2]; lp[3] = gp[3];
    }
    int node = blockIdx.x * 4 + (tid >> 6);   // grid*4 == N_NODES exactly
    int lane = tid & 63;
    float a0, a1, a2, a3; int deg;
    agg_core(node, lane, cnt, ssrc, t, a0, a1, a2, a3, deg);
    if ((lane & 32) == 0) {
        float inv = 1.f / fmaxf((float)deg, 1.f);
        int f = (lane & 31) * 4;
        ushort4 r = *(const ushort4*)(rootb + (size_t)node * 128 + f);
        float4 bb = *(const float4*)(bias + f);
        int nl = tid >> 6;
        // round through bf16 for numerical parity with the old hb path
        hL[nl][f + 0] = bf2f(f2bf(fmaxf(a0 * inv + bf2f(r.x) + bb.x, 0.f)));
        hL[nl][f + 1] = bf2f(f2bf(fmaxf(a1 * inv + bf2f(r.y) + bb.y, 0.f)));
        hL[nl][f + 2] = bf2f(f2bf(fmaxf(a2 * inv + bf2f(r.z) + bb.z, 0.f)));
        hL[nl][f + 3] = bf2f(f2bf(fmaxf(a3 * inv + bf2f(r.w) + bb.w, 0.f)));
    }
    __syncthreads();
    // 128 dots: thread t<128 handles (node t>>5, col t&31)
    if (tid < 128) {
        int nl = tid >> 5, b = tid & 31;
        const float* hp = hL[nl];
        const unsigned short* mp = &mebL[b * MEB_LD];
        float acc = 0.f;
        #pragma unroll 8
        for (int f = 0; f < 128; f++) acc += hp[f] * bf2f(mp[f]);
        sL[nl][b] = acc;
    }
    __syncthreads();
    if (tid < 128) {                      // coalesced S write: 512 contiguous bytes
        int nl = tid >> 5, b = tid & 31;
        S[(size_t)(blockIdx.x * 4 + nl) * 32 + b] = sL[nl][b];
    }
    if (tid < 32) {                       // per-block column stats over 4 rows
        float m = sL[0][tid], s = 1.f;
        #pragma unroll
        for (int r = 1; r < 4; r++) {
            float v = sL[r][tid];
            if (v > m) { s = s * __expf(m - v) + 1.f; m = v; }
            else       { s += __expf(v - m); }
        }
        pm[tid * NCHUNK + blockIdx.x] = m;
        ps[tid * NCHUNK + blockIdx.x] = s;
    }
}

// ---- merge: one block per column, reduce 12500 chunks -> cm/cl[32] ----
__global__ void __launch_bounds__(256) merge_k(const float* __restrict__ pm,
                                               const float* __restrict__ ps,
                                               float* __restrict__ cmg,
                                               float* __restrict__ clg) {
    __shared__ float sm[256], ss[256];
    int col = blockIdx.x;
    int t = threadIdx.x;
    float m = -3.4e38f, s = 0.f;
    for (int c = t; c < NCHUNK; c += 256) {
        float m2 = pm[col * NCHUNK + c], s2 = ps[col * NCHUNK + c];
        float M = fmaxf(m, m2);
        s = s * __expf(m - M) + s2 * __expf(m2 - M);
        m = M;
    }
    sm[t] = m; ss[t] = s;
    __syncthreads();
    for (int off = 128; off > 0; off >>= 1) {
        if (t < off) {
            float m2 = sm[t + off], s2 = ss[t + off];
            float M = fmaxf(sm[t], m2);
            ss[t] = ss[t] * __expf(sm[t] - M) + s2 * __expf(m2 - M);
            sm[t] = M;
        }
        __syncthreads();
    }
    if (t == 0) { cmg[col] = sm[0]; clg[col] = logf(ss[0]); }
}

// ---- final: element-wise subtract, full grid ----
__global__ void __launch_bounds__(256) final_k(const float* __restrict__ S,
                                               const float* __restrict__ cmg,
                                               const float* __restrict__ clg,
                                               float* __restrict__ out) {
    __shared__ float cc[32];
    int t = threadIdx.x;
    if (t < 32) cc[t] = cmg[t] + clg[t];
    __syncthreads();
    int idx = blockIdx.x * 256 + t;
    if (idx < N_NODES * 32) {
        int b = idx & 31;
        out[idx] = S[idx] - cc[b];
    }
}

extern "C" void kernel_launch(void* const* d_in, const int* in_sizes, int n_in,
                              void* d_out, int out_size, void* d_ws, size_t ws_size,
                              hipStream_t stream) {
    const float* x       = (const float*)d_in[0];
    const int*   ei      = (const int*)d_in[1];
    const float* lh      = (const float*)d_in[2];
    const float* W1_rel  = (const float*)d_in[3];
    const float* W1_root = (const float*)d_in[4];
    const float* b1      = (const float*)d_in[5];
    const float* W2_rel  = (const float*)d_in[6];
    const float* W2_root = (const float*)d_in[7];
    const float* b2      = (const float*)d_in[8];
    const float* Wp      = (const float*)d_in[9];
    const float* bp      = (const float*)d_in[10];
    float* out = (float*)d_out;
    float* ws  = (float*)d_ws;

    // workspace layout (float-element offsets; 16B alignment where needed)
    unsigned char*  tbf   = (unsigned char*)(ws + 3200000);     // fp8: 50001*128 B
    unsigned short* rootb = (unsigned short*)(ws + 4800032);    // 3,200,000 fl
    unsigned short* hb    = (unsigned short*)(ws + 8000032);    // 3,200,000 fl
    // S (1.6M fl) ALIASES hb: hb last read by step-6 gemm_dual_k; S first
    // written by step-7 aggscores_k.
    float* S = ws + 8000032;
    unsigned short* Wt1r  = (unsigned short*)(ws + 11200032);   // 8192 fl each
    unsigned short* Wt1o  = (unsigned short*)(ws + 11208224);
    unsigned short* Wt2r  = (unsigned short*)(ws + 11216416);
    unsigned short* Wt2o  = (unsigned short*)(ws + 11224608);
    unsigned short* MEb   = (unsigned short*)(ws + 11232800);   // 2048 fl
    float* cmg  = ws + 11284896;                                // 32
    float* clg  = ws + 11284928;                                // 32
    int*   cnt  = (int*)(ws + 11284960);                        // 50,000
    int*   blockcnt = (int*)(ws + 11384964);                    // 196*2500 = 490,000 ints
    int*   totals   = (int*)(ws + 11874964);                    // 196 (+pad)
    unsigned int* pairs = (unsigned int*)(ws + 11875220);       // 640,000 u32
    // pm/ps (400,000 fl each) ALIAS blockcnt/totals/pairs: those are dead after
    // step-4 placegemm; pm/ps first written step-7 aggscores.
    float* pm = ws + 11384964;                                  // 400,000
    float* ps = ws + 11784964;                                  // 400,000
    unsigned short* ssrc = (unsigned short*)(ws + 12519964);    // 2,800,000 u16

    const int* srcp = ei;
    const int* dstp = ei + N_EDGES;

    const int ew_grid  = (N_NODES * 32 + 255) / 256; // 6250
    const int agg_grid = (N_NODES + 3) / 4;          // 12500
    const int g32_grid = (N_NODES + 31) / 32;        // 1563

    // 1. prep: coarse LDS histogram (no device atomics) | weights | meb | dummy
    prep_k<<<2773, 256, 0, stream>>>(W1_rel, W1_root, W2_rel, W2_root,
                                     Wt1r, Wt1o, Wt2r, Wt2o,
                                     lh, Wp, bp, MEb, tbf, dstp, blockcnt);

    // 2. per-bucket exclusive scan over edge-blocks
    scan_k<<<NBUCK, 256, 0, stream>>>(blockcnt, totals);

    // 3. bucket-grouping scatter (LDS-ranked)
    scatter_k<<<EBLK, 256, 0, stream>>>(srcp, dstp, blockcnt, totals, pairs);

    // 4. placement (per-bucket LDS ranks -> ssrc/cnt) | layer-1 dual GEMM
    placegemm_k<<<NBUCK + g32_grid, 256, 0, stream>>>(totals, pairs, ssrc, cnt,
                                                      x, Wt1r, Wt1o, tbf, rootb);

    // 5. layer-1 aggregate (fp8 gather -> hb)
    agg_k<<<agg_grid, 256, 0, stream>>>(cnt, ssrc, tbf, rootb, b1, hb);

    // 6. layer-2 dual GEMM (bf16 A, LDS-staged A/B)
    gemm_dual_k<<<g32_grid, 256, 0, stream>>>(hb, Wt2r, Wt2o, tbf, rootb, N_NODES);

    // 7. FUSED layer-2 aggregate + scores + per-block column stats
    aggscores_k<<<agg_grid, 256, 0, stream>>>(cnt, ssrc, tbf, rootb, b2,
                                              MEb, S, pm, ps);

    // 8. merge column stats (32 blocks, 12500 chunks)
    merge_k<<<32, 256, 0, stream>>>(pm, ps, cmg, clg);

    // 9. final subtract (full grid)
    final_k<<<ew_grid, 256, 0, stream>>>(S, cmg, clg, out);
}

// Round 16
// 216.453 us; speedup vs baseline: 1.0659x; 1.0659x over previous
//
#include <hip/hip_runtime.h>
#include <hip/hip_bf16.h>

#define N_NODES 50000
#define N_EDGES 640000
#define DUMMY   N_NODES
#define PAD_SSRC 990000   // u16 slots; E + 7*N upper bound
// FEAT = EMB = 128, HID = 512, B = 32

typedef __attribute__((ext_vector_type(8))) short short8;   // 8 x bf16 (4 VGPRs)
typedef __attribute__((ext_vector_type(4))) float floatx4;  // MFMA C/D

__device__ __forceinline__ float bf2f(unsigned short u) {
    return __uint_as_float(((unsigned int)u) << 16);
}
__device__ __forceinline__ unsigned short f2bf(float x) {
    unsigned int u = __float_as_uint(x);
    u = (u + 0x7fffu + ((u >> 16) & 1u)) >> 16;   // RNE
    return (unsigned short)u;
}
__device__ __forceinline__ unsigned char f2f8(float x) {
    int pk = __builtin_amdgcn_cvt_pk_fp8_f32(x, x, 0, false);  // OCP e4m3 on gfx950
    return (unsigned char)(pk & 0xff);
}
__device__ __forceinline__ unsigned int pk4_fp8(float x0, float x1, float x2, float x3) {
    int v = __builtin_amdgcn_cvt_pk_fp8_f32(x0, x1, 0, false);
    v = __builtin_amdgcn_cvt_pk_fp8_f32(x2, x3, v, true);
    return (unsigned int)v;
}
__device__ __forceinline__ unsigned int pk2_bf16(float lo, float hi) {
    return (unsigned int)f2bf(lo) | ((unsigned int)f2bf(hi) << 16);
}

// ---- fused prep + histogram (hist INTERLEAVED with streaming branches) ----
__global__ void __launch_bounds__(256) prep_k(const float* __restrict__ W0,
                                              const float* __restrict__ W1,
                                              const float* __restrict__ W2,
                                              const float* __restrict__ W3,
                                              unsigned short* __restrict__ T0,
                                              unsigned short* __restrict__ T1,
                                              unsigned short* __restrict__ T2,
                                              unsigned short* __restrict__ T3,
                                              int* __restrict__ cnt,
                                              const float* __restrict__ lh,
                                              const float* __restrict__ Wp,
                                              const float* __restrict__ bp,
                                              unsigned short* __restrict__ meb,
                                              unsigned short* __restrict__ ssrc,
                                              unsigned char* __restrict__ tbf,
                                              int* __restrict__ total,
                                              const int* __restrict__ dst,
                                              int* __restrict__ rank) {
    int b = blockIdx.x, tid = threadIdx.x;
    bool is_hist;
    int idx;                              // hist-block index or stream-block index
    if (b < 4414) { is_hist = ((b & 1) == 0); idx = b >> 1; }
    else          { is_hist = true;            idx = 2207 + (b - 4414); }
    if (is_hist) {                        // histogram + packed rank: 2500 blocks
        int e = idx * 256 + tid;          // exactly 640000
        int d = dst[e];
        int r = atomicAdd(&cnt[d], 1);
        rank[e] = (r << 16) | d;
        return;
    }
    int s = idx;
    if (s < 256) {                        // pack weights transposed: 65536
        int i2 = s * 256 + tid;
        int w = i2 >> 14;
        int r = i2 & 16383;
        int n = r >> 7, k = r & 127;
        const float* W = (w == 0) ? W0 : (w == 1) ? W1 : (w == 2) ? W2 : W3;
        unsigned short* T = (w == 0) ? T0 : (w == 1) ? T1 : (w == 2) ? T2 : T3;
        T[r] = f2bf(W[k * 128 + n]);
    } else if (s < 272) {                 // message embed: 4096 outputs
        int o = (s - 256) * 256 + tid;
        int i = o >> 7, c = o & 127;
        float acc = bp[c];
        const float4* lr = (const float4*)(lh + i * 512);
        #pragma unroll 4
        for (int k4 = 0; k4 < 128; k4++) {
            float4 v = lr[k4];
            acc += v.x * Wp[(4 * k4 + 0) * 128 + c] + v.y * Wp[(4 * k4 + 1) * 128 + c]
                 + v.z * Wp[(4 * k4 + 2) * 128 + c] + v.w * Wp[(4 * k4 + 3) * 128 + c];
        }
        meb[o] = f2bf(acc);
    } else if (s < 2206) {                // fill padded ssrc with DUMMY (u16 pairs): 495000 u32
        int i = (s - 272) * 256 + tid;
        if (i < PAD_SSRC / 2) ((unsigned int*)ssrc)[i] = 0xC350C350u;
    } else {                              // zero dummy fp8 row (128 B) + total
        if (tid < 32) ((unsigned int*)(tbf + (size_t)DUMMY * 128))[tid] = 0;
        else if (tid == 32) *total = 0;
    }
}

// ---- dual GEMM, 32-row tiles, LDS-staged A and B (coalesced global reads) ----
// LDS pool: [0,8K) = A bf16 [32][128] swizzled; [8K,40K) = B bf16 [128][128]
// swizzled (per phase), later reused as the f32 epilogue tile.
// Swizzle (16B-granular): byte ^= ((row & 7) << 4), row = byte >> 8 (256B rows).
// Global reads: lane tid reads contiguous 16B chunks -> fully coalesced; the
// strided MFMA-fragment access happens in LDS (2-way conflict = free).
#define EPI_LD 132   // epilogue row stride in dwords
template <bool AF32>
__device__ __forceinline__ void gemm_dual_lds32(int bid, int tid,
                                                const void* __restrict__ Ain,
                                                const unsigned short* __restrict__ BtRel,
                                                const unsigned short* __restrict__ BtRoot,
                                                unsigned char* __restrict__ Trel,
                                                unsigned short* __restrict__ Rootb,
                                                int M, char* __restrict__ pool) {
    int wid = tid >> 6, lane = tid & 63;
    int m = lane & 15, g = lane >> 4;
    int r0 = bid * 32;
    // ---- stage A (coalesced, convert f32->bf16 in-flight if needed) ----
    if constexpr (AF32) {
        const float* A = (const float*)Ain;
        #pragma unroll
        for (int j = 0; j < 2; j++) {
            int k = j * 256 + tid;            // 16B-bf16 chunk id, 0..511
            int row = k >> 4;                 // 16 chunks per 256B bf16 row
            int grow = r0 + row; grow = (grow < M) ? grow : (M - 1);
            const float* p = A + (size_t)grow * 128 + (k & 15) * 8;
            float4 v0 = *(const float4*)p;
            float4 v1 = *(const float4*)(p + 4);
            short8 t8;
            t8[0] = (short)f2bf(v0.x); t8[1] = (short)f2bf(v0.y);
            t8[2] = (short)f2bf(v0.z); t8[3] = (short)f2bf(v0.w);
            t8[4] = (short)f2bf(v1.x); t8[5] = (short)f2bf(v1.y);
            t8[6] = (short)f2bf(v1.z); t8[7] = (short)f2bf(v1.w);
            *(short8*)(pool + ((k * 16) ^ ((row & 7) << 4))) = t8;
        }
    } else {
        const unsigned short* A = (const unsigned short*)Ain;
        #pragma unroll
        for (int j = 0; j < 2; j++) {
            int k = j * 256 + tid;
            int row = k >> 4;
            int grow = r0 + row; grow = (grow < M) ? grow : (M - 1);
            short8 v = *(const short8*)(A + (size_t)grow * 128 + (k & 15) * 8);
            *(short8*)(pool + ((k * 16) ^ ((row & 7) << 4))) = v;
        }
    }
    // ---- stage Brel (coalesced: 2048 x 16B chunks) ----
    #pragma unroll
    for (int j = 0; j < 8; j++) {
        int k = j * 256 + tid;                // 0..2047
        int row = k >> 4;
        short8 v = *(const short8*)(BtRel + (size_t)k * 8);
        *(short8*)(pool + 8192 + ((k * 16) ^ ((row & 7) << 4))) = v;
    }
    __syncthreads();
    // ---- A fragments from LDS ----
    int lrow = (wid >> 1) * 16 + m;
    int asw = (lrow & 7) << 4, abase = lrow * 256;
    short8 a[4];
    #pragma unroll
    for (int kt = 0; kt < 4; kt++)
        a[kt] = *(const short8*)(pool + ((abase + kt * 64 + g * 16) ^ asw));
    // ---- accR ----
    int browbase = (wid & 1) * 64;
    floatx4 accR[4], accO[4];
    #pragma unroll
    for (int ct = 0; ct < 4; ct++) {
        accR[ct] = (floatx4)(0.f);
        int brow = browbase + ct * 16 + m;
        int bbase = brow * 256, bsw = (brow & 7) << 4;
        #pragma unroll
        for (int kt = 0; kt < 4; kt++) {
            short8 bv = *(const short8*)(pool + 8192 + ((bbase + kt * 64 + g * 16) ^ bsw));
            accR[ct] = __builtin_amdgcn_mfma_f32_16x16x32_bf16(a[kt], bv, accR[ct], 0, 0, 0);
        }
    }
    __syncthreads();
    // ---- stage Broot (overwrite B region) ----
    #pragma unroll
    for (int j = 0; j < 8; j++) {
        int k = j * 256 + tid;
        int row = k >> 4;
        short8 v = *(const short8*)(BtRoot + (size_t)k * 8);
        *(short8*)(pool + 8192 + ((k * 16) ^ ((row & 7) << 4))) = v;
    }
    __syncthreads();
    // ---- accO ----
    #pragma unroll
    for (int ct = 0; ct < 4; ct++) {
        accO[ct] = (floatx4)(0.f);
        int brow = browbase + ct * 16 + m;
        int bbase = brow * 256, bsw = (brow & 7) << 4;
        #pragma unroll
        for (int kt = 0; kt < 4; kt++) {
            short8 bv = *(const short8*)(pool + 8192 + ((bbase + kt * 64 + g * 16) ^ bsw));
            accO[ct] = __builtin_amdgcn_mfma_f32_16x16x32_bf16(a[kt], bv, accO[ct], 0, 0, 0);
        }
    }
    __syncthreads();
    // ---- coalesced epilogue (epi aliases the B region) ----
    float* epi = (float*)(pool + 8192);
    int rh = (wid >> 1) * 16, ch = (wid & 1) * 64;
    #pragma unroll
    for (int ct = 0; ct < 4; ct++)
        #pragma unroll
        for (int rg = 0; rg < 4; rg++)
            epi[(rh + g * 4 + rg) * EPI_LD + ch + ct * 16 + m] = accR[ct][rg];
    __syncthreads();
    {
        int lr = tid >> 3, c0 = (tid & 7) * 16;   // 8 thr/row x 16 cols
        int ro = r0 + lr;
        const float* row = epi + lr * EPI_LD + c0;
        if (ro < M) {
            uint4 w;
            w.x = pk4_fp8(row[0],  row[1],  row[2],  row[3]);
            w.y = pk4_fp8(row[4],  row[5],  row[6],  row[7]);
            w.z = pk4_fp8(row[8],  row[9],  row[10], row[11]);
            w.w = pk4_fp8(row[12], row[13], row[14], row[15]);
            *(uint4*)(Trel + (size_t)ro * 128 + c0) = w;
        }
    }
    __syncthreads();
    #pragma unroll
    for (int ct = 0; ct < 4; ct++)
        #pragma unroll
        for (int rg = 0; rg < 4; rg++)
            epi[(rh + g * 4 + rg) * EPI_LD + ch + ct * 16 + m] = accO[ct][rg];
    __syncthreads();
    {
        int lr = tid >> 3, c0 = (tid & 7) * 16;
        int ro = r0 + lr;
        const float* row = epi + lr * EPI_LD + c0;
        if (ro < M) {
            uint4 w0, w1;
            w0.x = pk2_bf16(row[0],  row[1]);
            w0.y = pk2_bf16(row[2],  row[3]);
            w0.z = pk2_bf16(row[4],  row[5]);
            w0.w = pk2_bf16(row[6],  row[7]);
            w1.x = pk2_bf16(row[8],  row[9]);
            w1.y = pk2_bf16(row[10], row[11]);
            w1.z = pk2_bf16(row[12], row[13]);
            w1.w = pk2_bf16(row[14], row[15]);
            *(uint4*)(Rootb + (size_t)ro * 128 + c0) = w0;
            *(uint4*)(Rootb + (size_t)ro * 128 + c0 + 8) = w1;
        }
    }
}

// ---- merged: region allocator (blocks 0..195) | layer-1 dual GEMM (f32 A) ----
__global__ void __launch_bounds__(256) allocgemm_k(const int* __restrict__ cnt,
                                                   int* __restrict__ prow,
                                                   int* __restrict__ total,
                                                   const float* __restrict__ A,
                                                   const unsigned short* __restrict__ BtRel,
                                                   const unsigned short* __restrict__ BtRoot,
                                                   unsigned char* __restrict__ Trel,
                                                   unsigned short* __restrict__ Rootb) {
    __shared__ __align__(16) char pool[40960];
    if (blockIdx.x < 196) {
        int* sm = (int*)pool;
        int* base_s = (int*)(pool + 1024);
        int t = threadIdx.x;
        int i = blockIdx.x * 256 + t;
        int pc = (i < N_NODES) ? ((cnt[i] + 7) & ~7) : 0;
        sm[t] = pc;
        __syncthreads();
        for (int off = 1; off < 256; off <<= 1) {
            int v = (t >= off) ? sm[t - off] : 0;
            __syncthreads();
            sm[t] += v;
            __syncthreads();
        }
        if (t == 255) *base_s = atomicAdd(total, sm[255]);
        __syncthreads();
        if (i < N_NODES) prow[i] = *base_s + sm[t] - pc;
    } else {
        gemm_dual_lds32<true>(blockIdx.x - 196, threadIdx.x, A, BtRel, BtRoot,
                              Trel, Rootb, N_NODES, pool);
    }
}

// ---- placement: packed (rank,dst) -> single stream + prow gather + scatter ----
__global__ void __launch_bounds__(256) place_k(const int* __restrict__ src,
                                               const int* __restrict__ prow,
                                               const int* __restrict__ rank,
                                               unsigned short* __restrict__ ssrc) {
    int e = blockIdx.x * 256 + threadIdx.x;
    if (e < N_EDGES) {
        int pk = rank[e];
        int d = pk & 0xffff;
        int r = pk >> 16;
        ssrc[prow[d] + r] = (unsigned short)src[e];
    }
}

// ---- standalone dual GEMM (layer 2, bf16 A, 32-row tiles, LDS-staged) ----
__global__ void __launch_bounds__(256) gemm_dual_k(const unsigned short* __restrict__ A,
                                                   const unsigned short* __restrict__ BtRel,
                                                   const unsigned short* __restrict__ BtRoot,
                                                   unsigned char* __restrict__ Trel,
                                                   unsigned short* __restrict__ Rootb, int M) {
    __shared__ __align__(16) char pool[40960];
    gemm_dual_lds32<false>(blockIdx.x, threadIdx.x, A, BtRel, BtRoot, Trel, Rootb, M, pool);
}

// ---- gather-aggregate v8: fp8 table (128 B row), 2 rows/instr, 16 edges/round ----
__global__ void __launch_bounds__(256) agg_k(const int* __restrict__ prow,
                                             const int* __restrict__ cnt,
                                             const unsigned short* __restrict__ ssrc,
                                             const unsigned char* __restrict__ t,
                                             const unsigned short* __restrict__ rootb,
                                             const float* __restrict__ bias,
                                             unsigned short* __restrict__ hout) {
    int node = blockIdx.x * 4 + (threadIdx.x >> 6);
    if (node >= N_NODES) return;
    int lane = threadIdx.x & 63;
    int fl = lane & 31;                    // feature group (4 feats)
    int sh = (lane & 32) >> 1;             // 0 = even-edge half, 16 = odd-edge half
    int beg = prow[node];
    int deg = cnt[node];
    int endp = beg + ((deg + 7) & ~7);
    const unsigned char* tf = t + fl * 4;
    float a0=0.f,a1=0.f,a2=0.f,a3=0.f;
    float b0=0.f,b1=0.f,b2=0.f,b3=0.f;
    for (int e = beg; e < endp; e += 16) {
        uint4 w0 = *(const uint4*)(ssrc + e);
        uint4 w1 = (e + 8 < endp) ? *(const uint4*)(ssrc + e + 8)
                                  : make_uint4(0xC350C350u, 0xC350C350u, 0xC350C350u, 0xC350C350u);
        int i0 = (int)((w0.x >> sh) & 0xffffu);
        int i1 = (int)((w0.y >> sh) & 0xffffu);
        int i2 = (int)((w0.z >> sh) & 0xffffu);
        int i3 = (int)((w0.w >> sh) & 0xffffu);
        int i4 = (int)((w1.x >> sh) & 0xffffu);
        int i5 = (int)((w1.y >> sh) & 0xffffu);
        int i6 = (int)((w1.z >> sh) & 0xffffu);
        int i7 = (int)((w1.w >> sh) & 0xffffu);
        unsigned int u0 = *(const unsigned int*)(tf + (size_t)i0 * 128);
        unsigned int u1 = *(const unsigned int*)(tf + (size_t)i1 * 128);
        unsigned int u2 = *(const unsigned int*)(tf + (size_t)i2 * 128);
        unsigned int u3 = *(const unsigned int*)(tf + (size_t)i3 * 128);
        unsigned int u4 = *(const unsigned int*)(tf + (size_t)i4 * 128);
        unsigned int u5 = *(const unsigned int*)(tf + (size_t)i5 * 128);
        unsigned int u6 = *(const unsigned int*)(tf + (size_t)i6 * 128);
        unsigned int u7 = *(const unsigned int*)(tf + (size_t)i7 * 128);
        a0 += __builtin_amdgcn_cvt_f32_fp8(u0, 0) + __builtin_amdgcn_cvt_f32_fp8(u1, 0);
        a1 += __builtin_amdgcn_cvt_f32_fp8(u0, 1) + __builtin_amdgcn_cvt_f32_fp8(u1, 1);
        a2 += __builtin_amdgcn_cvt_f32_fp8(u0, 2) + __builtin_amdgcn_cvt_f32_fp8(u1, 2);
        a3 += __builtin_amdgcn_cvt_f32_fp8(u0, 3) + __builtin_amdgcn_cvt_f32_fp8(u1, 3);
        b0 += __builtin_amdgcn_cvt_f32_fp8(u2, 0) + __builtin_amdgcn_cvt_f32_fp8(u3, 0);
        b1 += __builtin_amdgcn_cvt_f32_fp8(u2, 1) + __builtin_amdgcn_cvt_f32_fp8(u3, 1);
        b2 += __builtin_amdgcn_cvt_f32_fp8(u2, 2) + __builtin_amdgcn_cvt_f32_fp8(u3, 2);
        b3 += __builtin_amdgcn_cvt_f32_fp8(u2, 3) + __builtin_amdgcn_cvt_f32_fp8(u3, 3);
        a0 += __builtin_amdgcn_cvt_f32_fp8(u4, 0) + __builtin_amdgcn_cvt_f32_fp8(u5, 0);
        a1 += __builtin_amdgcn_cvt_f32_fp8(u4, 1) + __builtin_amdgcn_cvt_f32_fp8(u5, 1);
        a2 += __builtin_amdgcn_cvt_f32_fp8(u4, 2) + __builtin_amdgcn_cvt_f32_fp8(u5, 2);
        a3 += __builtin_amdgcn_cvt_f32_fp8(u4, 3) + __builtin_amdgcn_cvt_f32_fp8(u5, 3);
        b0 += __builtin_amdgcn_cvt_f32_fp8(u6, 0) + __builtin_amdgcn_cvt_f32_fp8(u7, 0);
        b1 += __builtin_amdgcn_cvt_f32_fp8(u6, 1) + __builtin_amdgcn_cvt_f32_fp8(u7, 1);
        b2 += __builtin_amdgcn_cvt_f32_fp8(u6, 2) + __builtin_amdgcn_cvt_f32_fp8(u7, 2);
        b3 += __builtin_amdgcn_cvt_f32_fp8(u6, 3) + __builtin_amdgcn_cvt_f32_fp8(u7, 3);
    }
    a0 += b0; a1 += b1; a2 += b2; a3 += b3;
    a0 += __shfl_xor(a0, 32);
    a1 += __shfl_xor(a1, 32);
    a2 += __shfl_xor(a2, 32);
    a3 += __shfl_xor(a3, 32);
    if ((lane & 32) == 0) {
        float inv = 1.f / fmaxf((float)deg, 1.f);
        int f = fl * 4;
        ushort4 r = *(const ushort4*)(rootb + (size_t)node * 128 + f);
        float4 bb = *(const float4*)(bias + f);
        ushort4 o;
        o.x = f2bf(fmaxf(a0 * inv + bf2f(r.x) + bb.x, 0.f));
        o.y = f2bf(fmaxf(a1 * inv + bf2f(r.y) + bb.y, 0.f));
        o.z = f2bf(fmaxf(a2 * inv + bf2f(r.z) + bb.z, 0.f));
        o.w = f2bf(fmaxf(a3 * inv + bf2f(r.w) + bb.w, 0.f));
        *(ushort4*)(hout + (size_t)node * 128 + f) = o;
    }
}

// ---- scores MFMA GEMM fused with per-block column stats ----
__global__ void __launch_bounds__(256) scores_cs_k(const unsigned short* __restrict__ A,
                                                   const unsigned short* __restrict__ Bt,
                                                   float* __restrict__ S,
                                                   float* __restrict__ pm,
                                                   float* __restrict__ ps) {
    __shared__ float Sl[64][33];
    __shared__ float sm[256], ss[256];
    int tid = threadIdx.x;
    int wid = tid >> 6, lane = tid & 63;
    int r0 = blockIdx.x * 64 + wid * 16;
    int m = lane & 15, g = lane >> 4;
    int row = r0 + m;
    int rowc = (row < N_NODES) ? row : (N_NODES - 1);
    short8 a[4];
    #pragma unroll
    for (int kt = 0; kt < 4; kt++)
        a[kt] = *(const short8*)(A + (size_t)rowc * 128 + kt * 32 + g * 8);
    floatx4 acc[2];
    acc[0] = (floatx4)(0.f);
    acc[1] = (floatx4)(0.f);
    #pragma unroll
    for (int ct = 0; ct < 2; ct++) {
        const unsigned short* b = Bt + (size_t)(ct * 16 + m) * 128 + g * 8;
        #pragma unroll
        for (int kt = 0; kt < 4; kt++) {
            short8 bv = *(const short8*)(b + kt * 32);
            acc[ct] = __builtin_amdgcn_mfma_f32_16x16x32_bf16(a[kt], bv, acc[ct], 0, 0, 0);
        }
    }
    #pragma unroll
    for (int ct = 0; ct < 2; ct++) {
        #pragma unroll
        for (int rg = 0; rg < 4; rg++) {
            int lr = wid * 16 + g * 4 + rg;
            int ro = r0 + g * 4 + rg;
            Sl[lr][ct * 16 + m] = acc[ct][rg];
            if (ro < N_NODES) S[(size_t)ro * 32 + ct * 16 + m] = acc[ct][rg];
        }
    }
    __syncthreads();
    int col = tid & 31, sub = tid >> 5;
    int blkbase = blockIdx.x * 64;
    float mm = -3.4e38f, s = 0.f;
    for (int r = sub; r < 64; r += 8) {
        if (blkbase + r < N_NODES) {
            float v = Sl[r][col];
            if (v > mm) { s = s * __expf(mm - v) + 1.f; mm = v; }
            else        { s += __expf(v - mm); }
        }
    }
    sm[tid] = mm; ss[tid] = s;
    __syncthreads();
    for (int off = 128; off >= 32; off >>= 1) {
        if (tid < off) {
            float m2 = sm[tid + off], s2 = ss[tid + off];
            float M = fmaxf(sm[tid], m2);
            ss[tid] = ss[tid] * __expf(sm[tid] - M) + s2 * __expf(m2 - M);
            sm[tid] = M;
        }
        __syncthreads();
    }
    if (tid < 32) { pm[tid * 782 + blockIdx.x] = sm[tid]; ps[tid * 782 + blockIdx.x] = ss[tid]; }
}

// ---- merge: one block per column, reduce 782 chunks -> cm/cl[32] ----
__global__ void __launch_bounds__(256) merge_k(const float* __restrict__ pm,
                                               const float* __restrict__ ps,
                                               float* __restrict__ cmg,
                                               float* __restrict__ clg) {
    __shared__ float sm[256], ss[256];
    int col = blockIdx.x;
    int t = threadIdx.x;
    float m = -3.4e38f, s = 0.f;
    for (int c = t; c < 782; c += 256) {
        float m2 = pm[col * 782 + c], s2 = ps[col * 782 + c];
        float M = fmaxf(m, m2);
        s = s * __expf(m - M) + s2 * __expf(m2 - M);
        m = M;
    }
    sm[t] = m; ss[t] = s;
    __syncthreads();
    for (int off = 128; off > 0; off >>= 1) {
        if (t < off) {
            float m2 = sm[t + off], s2 = ss[t + off];
            float M = fmaxf(sm[t], m2);
            ss[t] = ss[t] * __expf(sm[t] - M) + s2 * __expf(m2 - M);
            sm[t] = M;
        }
        __syncthreads();
    }
    if (t == 0) { cmg[col] = sm[0]; clg[col] = logf(ss[0]); }
}

// ---- final: element-wise subtract, full grid ----
__global__ void __launch_bounds__(256) final_k(const float* __restrict__ S,
                                               const float* __restrict__ cmg,
                                               const float* __restrict__ clg,
                                               float* __restrict__ out) {
    __shared__ float cc[32];
    int t = threadIdx.x;
    if (t < 32) cc[t] = cmg[t] + clg[t];
    __syncthreads();
    int idx = blockIdx.x * 256 + t;
    if (idx < N_NODES * 32) {
        int b = idx & 31;
        out[idx] = S[idx] - cc[b];
    }
}

extern "C" void kernel_launch(void* const* d_in, const int* in_sizes, int n_in,
                              void* d_out, int out_size, void* d_ws, size_t ws_size,
                              hipStream_t stream) {
    const float* x       = (const float*)d_in[0];
    const int*   ei      = (const int*)d_in[1];
    const float* lh      = (const float*)d_in[2];
    const float* W1_rel  = (const float*)d_in[3];
    const float* W1_root = (const float*)d_in[4];
    const float* b1      = (const float*)d_in[5];
    const float* W2_rel  = (const float*)d_in[6];
    const float* W2_root = (const float*)d_in[7];
    const float* b2      = (const float*)d_in[8];
    const float* Wp      = (const float*)d_in[9];
    const float* bp      = (const float*)d_in[10];
    float* out = (float*)d_out;
    float* ws  = (float*)d_ws;

    // workspace layout (float-element offsets; 16B alignment where needed)
    unsigned char*  tbf   = (unsigned char*)(ws + 3200000);     // fp8: 50001*128 B = 1,600,032 fl
    unsigned short* rootb = (unsigned short*)(ws + 4800032);    // 3,200,000 fl
    unsigned short* hb    = (unsigned short*)(ws + 8000032);    // 3,200,000 fl
    unsigned short* Wt1r  = (unsigned short*)(ws + 11200032);   // 8192 fl each
    unsigned short* Wt1o  = (unsigned short*)(ws + 11208224);
    unsigned short* Wt2r  = (unsigned short*)(ws + 11216416);
    unsigned short* Wt2o  = (unsigned short*)(ws + 11224608);
    unsigned short* MEb   = (unsigned short*)(ws + 11232800);   // 2048 fl
    float* pm   = ws + 11234848;                                // 25,024
    float* ps   = ws + 11259872;                                // 25,024
    float* cmg  = ws + 11284896;                                // 32
    float* clg  = ws + 11284928;                                // 32
    int*   cnt  = (int*)(ws + 11284960);                        // 50,000
    int*   prow = (int*)(ws + 11334960);                        // 50,001
    int*   total= (int*)(ws + 11384961);                        // 1
    int*   rank = (int*)(ws + 11384964);                        // 640,000 (packed rank<<16|dst)
    unsigned short* ssrc = (unsigned short*)(ws + 12024964);    // 990,000 u16 (16B-aligned)
    float* S    = ws + 12519964;                                // 1,600,000

    const int* srcp = ei;
    const int* dstp = ei + N_EDGES;

    const int e_grid   = (N_EDGES + 255) / 256;      // 2500
    const int ew_grid  = (N_NODES * 32 + 255) / 256; // 6250
    const int agg_grid = (N_NODES + 3) / 4;          // 12500
    const int mm_grid  = (N_NODES + 63) / 64;        // 782
    const int g32_grid = (N_NODES + 31) / 32;        // 1563 (32-row GEMM tiles)

    // 0. zero cnt (graph memset node) — prerequisite for the hist blocks in prep_k
    hipMemsetAsync(cnt, 0, N_NODES * sizeof(int), stream);

    // 1. fused prep + histogram (hist blocks interleaved with streaming blocks)
    prep_k<<<4707, 256, 0, stream>>>(W1_rel, W1_root, W2_rel, W2_root,
                                     Wt1r, Wt1o, Wt2r, Wt2o,
                                     cnt, lh, Wp, bp, MEb, ssrc, tbf, total,
                                     dstp, rank);

    // 2. region allocator | layer-1 dual GEMM (f32 A, LDS-staged A/B)
    allocgemm_k<<<196 + g32_grid, 256, 0, stream>>>(cnt, prow, total,
                                                    x, Wt1r, Wt1o, tbf, rootb);

    // 3. placement (packed rank stream)
    place_k<<<e_grid, 256, 0, stream>>>(srcp, prow, rank, ssrc);

    // 4. layer-1 aggregate (fp8 gather)
    agg_k<<<agg_grid, 256, 0, stream>>>(prow, cnt, ssrc, tbf, rootb, b1, hb);

    // 5. layer-2 dual GEMM (bf16 A, LDS-staged A/B)
    gemm_dual_k<<<g32_grid, 256, 0, stream>>>(hb, Wt2r, Wt2o, tbf, rootb, N_NODES);

    // 6. layer-2 aggregate (fp8 gather)
    agg_k<<<agg_grid, 256, 0, stream>>>(prow, cnt, ssrc, tbf, rootb, b2, hb);

    // 7. scores GEMM + fused per-block column stats
    scores_cs_k<<<mm_grid, 256, 0, stream>>>(hb, MEb, S, pm, ps);

    // 8. merge column stats (32 blocks)
    merge_k<<<32, 256, 0, stream>>>(pm, ps, cmg, clg);

    // 9. final subtract (full grid)
    final_k<<<ew_grid, 256, 0, stream>>>(S, cmg, clg, out);
}